// Round 7
// baseline (2928.234 us; speedup 1.0000x reference)
//
#include <hip/hip_runtime.h>

#define Bsz 128
#define Lseq 512
#define Hdim 256
#define Tn 16
#define START_TAG 14
#define END_TAG 15
#define HSTRIDE 148   // uints; (148*4)%16==0 for b128 alignment, 2-way LDS banks max

typedef float f32x4 __attribute__((ext_vector_type(4)));
typedef short s16x8 __attribute__((ext_vector_type(8)));

__device__ __forceinline__ unsigned short f2bf(float f) {
    unsigned int u = __builtin_bit_cast(unsigned int, f);
    u += 0x7fffu + ((u >> 16) & 1u);          // RNE
    return (unsigned short)(u >> 16);
}
__device__ __forceinline__ float bf2f(unsigned int bits16) {
    return __builtin_bit_cast(float, bits16 << 16);
}
__device__ __forceinline__ float sigmoidf_(float x) {
    return 1.0f / (1.0f + __expf(-x));
}

// emb fp32 [V*256] -> packed bf16 pairs [V*128]
__global__ void embprep_kernel(const float* __restrict__ emb,
                               unsigned int* __restrict__ embb, int n2) {
    int i = blockIdx.x * blockDim.x + threadIdx.x;
    int stride = gridDim.x * blockDim.x;
    for (; i < n2; i += stride)
        embb[i] = (unsigned int)f2bf(emb[2 * i]) | ((unsigned int)f2bf(emb[2 * i + 1]) << 16);
}

// wtile[dir][ug(16)][wv(4)][ki(16)][lane(64)][4 uints] : MFMA B-frag order.
// lane l: n=l&15, kq=l>>4; col(n,wv) = (n&3)*256 + ug*16 + wv*4 + (n>>2)
// (gate in n's low 2 bits -> all 4 gates of a unit live in adjacent lanes).
__global__ void wprep_kernel(const float* __restrict__ wih_f, const float* __restrict__ whh_f,
                             const float* __restrict__ wih_b, const float* __restrict__ whh_b,
                             unsigned int* __restrict__ wtile) {
    int bid = blockIdx.x;                 // ((dir*16+ug)*4+wv)*16+ki
    int ki  = bid & 15;
    int wv  = (bid >> 4) & 3;
    int ug  = (bid >> 6) & 15;
    int dir = bid >> 10;
    int t = threadIdx.x;                  // 256 = lane(64) x j(4)
    int lane = t >> 2, j = t & 3;
    int n = lane & 15, kq = lane >> 4;
    int k0 = ki * 32 + kq * 8 + 2 * j;
    int col = (n & 3) * 256 + ug * 16 + wv * 4 + (n >> 2);
    const float* wih = dir ? wih_b : wih_f;
    const float* whh = dir ? whh_b : whh_f;
    float f0, f1;
    if (k0 < 256) { f0 = wih[col * 256 + k0];       f1 = wih[col * 256 + k0 + 1]; }
    else          { f0 = whh[col * 256 + k0 - 256]; f1 = whh[col * 256 + k0 - 255]; }
    wtile[(size_t)bid * 256 + t] = (unsigned int)f2bf(f0) | ((unsigned int)f2bf(f1) << 16);
}

__global__ void lengths_kernel(const int* __restrict__ tag, int* __restrict__ lengths) {
    int b = blockIdx.x;
    int tid = threadIdx.x;
    int cnt = 0;
    for (int l = tid; l < Lseq; l += blockDim.x)
        cnt += (tag[b * Lseq + l] != 0) ? 1 : 0;
    for (int off = 32; off > 0; off >>= 1) cnt += __shfl_down(cnt, off);
    __shared__ int red[4];
    if ((tid & 63) == 0) red[tid >> 6] = cnt;
    __syncthreads();
    if (tid == 0) lengths[b] = red[0] + red[1] + red[2] + red[3];
}

// Persistent BiLSTM, 256 WGs (1/CU). WG = dir(2) x bg(8: 16 batches) x ug(16: 16 units).
// Release: tagged h stores (epoch LSBs) then per-wave monotonic flag, NO drain.
// Acquire: poll the group's 64 flag words (4 lines, 1 load/iter), then bulk-load
// h and verify per-word tags (retries ~0 since flag was issued after data).
// Ring layout [slot][ug][batch][8 uints]: each WG writes 512 B of full lines.
__global__ __launch_bounds__(256, 1) void bilstm_persist(
    const int* __restrict__ bd,
    const unsigned int* __restrict__ embb,     // [V][128]
    const unsigned int* __restrict__ wtile,    // frag-ordered weights
    const float* __restrict__ b_f, const float* __restrict__ b_b,
    const float* __restrict__ w_cls,
    float* __restrict__ em_f, float* __restrict__ em_b,
    unsigned int* __restrict__ ring,           // [2 dir][2 slot][16 ug][128 b][8]
    int* __restrict__ flags)                   // [16 grp][64]
{
    const int wg  = blockIdx.x;
    const int dir = wg >> 7;
    const int bg  = (wg >> 4) & 7;
    const int ug  = wg & 15;
    const int grp = dir * 8 + bg;
    const int tid = threadIdx.x;
    const int gb0 = bg * 16;

    __shared__ unsigned int h_lds[2][16 * HSTRIDE];
    __shared__ float wcls_lds[256];

    wcls_lds[tid] = w_cls[(size_t)ug * (2 * Hdim) + dir * Hdim + tid];

    const int wv = tid >> 6;
    const int l  = tid & 63;
    const int n  = l & 15;
    const int kq = l >> 4;

    // ---- weights into registers (16 x uint4) ----
    uint4 w_reg[16];
    {
        const unsigned int* wsrc =
            wtile + ((size_t)((dir * 16 + ug) * 4 + wv) * 16) * 256 + l * 4;
        #pragma unroll
        for (int ki = 0; ki < 16; ++ki)
            w_reg[ki] = *(const uint4*)(wsrc + ki * 256);
    }
    const float bias_lane = (dir ? b_b : b_f)[(n & 3) * 256 + ug * 16 + wv * 4 + (n >> 2)];
    float c_reg[4] = {0.f, 0.f, 0.f, 0.f};
    const int* bdr = bd + (size_t)(gb0 + n) * Lseq;
    unsigned int* rb = ring + (size_t)dir * 32768;
    int* flg = &flags[grp * 64];
    const bool storer = ((l & 7) == 0);            // n in {0,8}
    const int store_off = wv * 2 + (n >> 3);       // uint col within 8-uint chunk
    float* emout = dir ? em_b : em_f;

    // stage identity: thread loads chunk c=tid&15 (peer ug'), row m=tid>>4
    const int sc = tid & 15, sm = tid >> 4;

    // emission identity: batch_e per wave, k-seg per lane
    const int batch_e = wv * 4 + (kq);             // kq = l>>4: 4 batches/wave
    const int kseg = n;                            // 16 k-segments

    __syncthreads();   // wcls ready

    // ---- prologue: acc_x for s=0 ----
    f32x4 acc_x = {0.f, 0.f, 0.f, 0.f};
    {
        const int t0 = dir ? (Lseq - 1) : 0;
        int tok = bdr[t0];
        const unsigned int* xsrc = embb + (size_t)tok * 128 + kq * 4;
        #pragma unroll
        for (int ki = 0; ki < 8; ++ki) {
            s16x8 a = __builtin_bit_cast(s16x8, *(const uint4*)(xsrc + ki * 16));
            acc_x = __builtin_amdgcn_mfma_f32_16x16x32_bf16(
                a, __builtin_bit_cast(s16x8, w_reg[ki]), acc_x, 0, 0, 0);
        }
    }

    for (int s = 0; s < Lseq; ++s) {
        // ---- 1: poll group flags (monotonic >= s); one line-group load/iter ----
        if (s > 0) {
            while (true) {
                int v = __hip_atomic_load(&flg[l], __ATOMIC_RELAXED, __HIP_MEMORY_SCOPE_AGENT);
                if (__all(v >= s)) break;
            }
        }

        // ---- 2: stage h_{s-1}: bulk load + tag verify (retry rare) ----
        {
            const unsigned int* src = rb + ((s + 1) & 1) * 16384 + sc * 1024 + (gb0 + sm) * 8;
            const unsigned int want = (((s + 3) >> 1) & 1) * 0x00010001u;
            unsigned int v[8];
            #pragma unroll
            for (int j = 0; j < 8; ++j)
                v[j] = __hip_atomic_load(src + j, __ATOMIC_RELAXED, __HIP_MEMORY_SCOPE_AGENT);
            bool again = true;
            while (again) {
                again = false;
                #pragma unroll
                for (int j = 0; j < 8; ++j)
                    if ((v[j] & 0x00010001u) != want) {
                        v[j] = __hip_atomic_load(src + j, __ATOMIC_RELAXED,
                                                 __HIP_MEMORY_SCOPE_AGENT);
                        again = true;
                    }
            }
            unsigned int* dst = &h_lds[s & 1][sm * HSTRIDE + sc * 8];
            *(uint4*)dst       = make_uint4(v[0], v[1], v[2], v[3]);
            *(uint4*)(dst + 4) = make_uint4(v[4], v[5], v[6], v[7]);
        }
        __syncthreads();
        const unsigned int* hb = &h_lds[s & 1][0];

        // ---- 3: issue x loads for s+1 (consumed after the h store) ----
        uint4 xf[8];
        const bool havex = (s + 1 < Lseq);
        if (havex) {
            const int tn = dir ? (Lseq - 2 - s) : (s + 1);
            int tok = bdr[tn];
            const unsigned int* xsrc = embb + (size_t)tok * 128 + kq * 4;
            #pragma unroll
            for (int ki = 0; ki < 8; ++ki)
                xf[ki] = *(const uint4*)(xsrc + ki * 16);
        }

        // ---- 4: 8 h-MFMAs on top of acc_x ----
        f32x4 acc = acc_x;
        #pragma unroll
        for (int kih = 0; kih < 8; ++kih) {
            s16x8 a = *(const s16x8*)&hb[n * HSTRIDE + kih * 16 + kq * 4];
            acc = __builtin_amdgcn_mfma_f32_16x16x32_bf16(
                a, __builtin_bit_cast(s16x8, w_reg[8 + kih]), acc, 0, 0, 0);
        }

        // ---- 5: cell update + tagged full-line h store ----
        {
            const unsigned int ep = (unsigned int)((s >> 1) & 1);
            const int base = l & ~3;
            unsigned int hbits[4];
            #pragma unroll
            for (int r = 0; r < 4; ++r) {
                float pre = acc[r] + bias_lane;
                float gi = __shfl(pre, base);
                float gf = __shfl(pre, base + 1);
                float gg = __shfl(pre, base + 2);
                float go = __shfl(pre, base + 3);
                float cn = sigmoidf_(gf) * c_reg[r] + sigmoidf_(gi) * tanhf(gg);
                c_reg[r] = cn;
                float hn = sigmoidf_(go) * tanhf(cn);
                hbits[r] = ((unsigned int)f2bf(hn) & 0xFFFEu) | ep;
            }
            unsigned int* dstrow = rb + (s & 1) * 16384 + ug * 1024;
            #pragma unroll
            for (int r = 0; r < 4; ++r) {
                unsigned int partner = (unsigned int)__shfl((int)hbits[r], l + 4);
                if (storer) {
                    unsigned int pk = hbits[r] | (partner << 16);
                    __hip_atomic_store(dstrow + (gb0 + kq * 4 + r) * 8 + store_off, pk,
                                       __ATOMIC_RELAXED, __HIP_MEMORY_SCOPE_AGENT);
                }
            }
        }

        // ---- 6: per-wave flag (fire-and-forget; tags are the real guarantee) ----
        if (l == 0)
            __hip_atomic_store(&flg[ug * 4 + wv], s + 1,
                               __ATOMIC_RELAXED, __HIP_MEMORY_SCOPE_AGENT);

        // ---- 7: x-half MFMAs for s+1 (hidden in propagation window) ----
        if (havex) {
            f32x4 ax = {0.f, 0.f, 0.f, 0.f};
            #pragma unroll
            for (int ki = 0; ki < 8; ++ki) {
                ax = __builtin_amdgcn_mfma_f32_16x16x32_bf16(
                    __builtin_bit_cast(s16x8, xf[ki]),
                    __builtin_bit_cast(s16x8, w_reg[ki]), ax, 0, 0, 0);
            }
            acc_x = ax;
        }

        // ---- 8: emission for t_prev from staged h (hidden) ----
        if (s > 0) {
            const unsigned int* hr = &hb[batch_e * HSTRIDE + kseg * 8];
            float p = 0.f;
            #pragma unroll
            for (int j = 0; j < 8; ++j) {
                unsigned int v = hr[j];
                int k0 = kseg * 16 + 2 * j;
                p += bf2f(v & 0xffffu) * wcls_lds[k0] + bf2f(v >> 16) * wcls_lds[k0 + 1];
            }
            #pragma unroll
            for (int m = 1; m < 16; m <<= 1) p += __shfl_xor(p, m);
            if (n == 0) {
                int t_prev = dir ? (Lseq - s) : (s - 1);
                emout[((size_t)(gb0 + batch_e) * Lseq + t_prev) * Tn + ug] = p;
            }
        }
    }

    // ---- tail: emission for h_{L-1} ----
    {
        const int s = Lseq;
        while (true) {
            int v = __hip_atomic_load(&flg[l], __ATOMIC_RELAXED, __HIP_MEMORY_SCOPE_AGENT);
            if (__all(v >= s)) break;
        }
        const unsigned int* src = rb + ((s + 1) & 1) * 16384 + sc * 1024 + (gb0 + sm) * 8;
        const unsigned int want = (((s + 3) >> 1) & 1) * 0x00010001u;
        unsigned int v[8];
        #pragma unroll
        for (int j = 0; j < 8; ++j)
            v[j] = __hip_atomic_load(src + j, __ATOMIC_RELAXED, __HIP_MEMORY_SCOPE_AGENT);
        bool again = true;
        while (again) {
            again = false;
            #pragma unroll
            for (int j = 0; j < 8; ++j)
                if ((v[j] & 0x00010001u) != want) {
                    v[j] = __hip_atomic_load(src + j, __ATOMIC_RELAXED,
                                             __HIP_MEMORY_SCOPE_AGENT);
                    again = true;
                }
        }
        unsigned int* dst = &h_lds[s & 1][sm * HSTRIDE + sc * 8];
        *(uint4*)dst       = make_uint4(v[0], v[1], v[2], v[3]);
        *(uint4*)(dst + 4) = make_uint4(v[4], v[5], v[6], v[7]);
        __syncthreads();
        const unsigned int* hb = &h_lds[s & 1][0];
        {
            const unsigned int* hr = &hb[batch_e * HSTRIDE + kseg * 8];
            float p = 0.f;
            #pragma unroll
            for (int j = 0; j < 8; ++j) {
                unsigned int vv = hr[j];
                int k0 = kseg * 16 + 2 * j;
                p += bf2f(vv & 0xffffu) * wcls_lds[k0] + bf2f(vv >> 16) * wcls_lds[k0 + 1];
            }
            #pragma unroll
            for (int m = 1; m < 16; m <<= 1) p += __shfl_xor(p, m);
            if (n == 0) {
                int t_tail = dir ? 0 : (Lseq - 1);
                emout[((size_t)(gb0 + batch_e) * Lseq + t_tail) * Tn + ug] = p;
            }
        }
    }
}

__global__ void golden_kernel(const int* __restrict__ tag,
                              const float* __restrict__ em_f,
                              const float* __restrict__ em_b,
                              const float* __restrict__ b_cls,
                              const float* __restrict__ trans,
                              float* __restrict__ golden)
{
    int b = blockIdx.x;
    int tid = threadIdx.x;
    float s = 0.f;
    for (int l = tid; l < Lseq; l += blockDim.x) {
        int tg = tag[b * Lseq + l];
        if (tg != 0) {
            int prev = (l == 0) ? START_TAG : tag[b * Lseq + l - 1];
            size_t e = ((size_t)b * Lseq + l) * Tn + tg;
            s += em_f[e] + em_b[e] + b_cls[tg] + trans[prev * Tn + tg];
        }
    }
    for (int off = 32; off > 0; off >>= 1) s += __shfl_down(s, off);
    __shared__ float red[4];
    if ((tid & 63) == 0) red[tid >> 6] = s;
    __syncthreads();
    if (tid == 0) atomicAdd(golden, red[0] + red[1] + red[2] + red[3]);
}

__global__ void crf_forward_kernel(const float* __restrict__ em_f,
                                   const float* __restrict__ em_b,
                                   const float* __restrict__ b_cls,
                                   const float* __restrict__ trans,
                                   const int* __restrict__ lengths,
                                   float* __restrict__ allpath)
{
    int b = blockIdx.x;
    int lane = threadIdx.x;
    int j = lane & 15;
    float tcol[16];
    #pragma unroll
    for (int i = 0; i < 16; ++i) tcol[i] = trans[i * Tn + j];
    float bc = b_cls[j];
    size_t e0 = ((size_t)b * Lseq) * Tn + j;
    float alpha = em_f[e0] + em_b[e0] + bc + tcol[START_TAG];
    int len = lengths[b];
    for (int t = 1; t < Lseq; ++t) {
        float av[16];
        float m = -1e30f;
        #pragma unroll
        for (int i = 0; i < 16; ++i) {
            av[i] = __shfl(alpha, i) + tcol[i];
            m = fmaxf(m, av[i]);
        }
        float sum = 0.f;
        #pragma unroll
        for (int i = 0; i < 16; ++i) sum += __expf(av[i] - m);
        size_t e = ((size_t)b * Lseq + t) * Tn + j;
        float nv = em_f[e] + em_b[e] + bc + m + __logf(sum);
        alpha = (t < len) ? nv : alpha;
    }
    if (lane == END_TAG) atomicAdd(allpath, alpha);
}

__global__ void finalize_kernel(const float* __restrict__ scal, float* __restrict__ out) {
    out[0] = (scal[1] - scal[0]) / (float)Bsz;
}

extern "C" void kernel_launch(void* const* d_in, const int* in_sizes, int n_in,
                              void* d_out, int out_size, void* d_ws, size_t ws_size,
                              hipStream_t stream)
{
    (void)in_sizes; (void)n_in; (void)out_size; (void)ws_size;
    const int*   bd     = (const int*)d_in[0];
    const int*   tag    = (const int*)d_in[1];
    const float* emb    = (const float*)d_in[2];
    const float* w_ih_f = (const float*)d_in[3];
    const float* w_hh_f = (const float*)d_in[4];
    const float* b_f    = (const float*)d_in[5];
    const float* w_ih_b = (const float*)d_in[6];
    const float* w_hh_b = (const float*)d_in[7];
    const float* b_b    = (const float*)d_in[8];
    const float* w_cls  = (const float*)d_in[9];
    const float* b_cls  = (const float*)d_in[10];
    const float* trans  = (const float*)d_in[11];
    float* out = (float*)d_out;

    float* ws = (float*)d_ws;
    float* em_f = ws;                                        // 1048576 f
    float* em_b = em_f + (size_t)Bsz * Lseq * Tn;            // 1048576 f
    unsigned int* ring = (unsigned int*)(em_b + (size_t)Bsz * Lseq * Tn);  // 65536 u
    float* scal = (float*)(ring + 65536);                    // 8 f
    int* flags = (int*)(scal + 8);                           // 16*64 = 1024
    int* lengths = flags + 1024;                             // 128
    unsigned int* wtile = (unsigned int*)(lengths + 128);    // 524288
    unsigned int* embb = wtile + (size_t)524288;             // 30000*128

    // ring pre-fill: 0x01 bytes -> bf16 halves ~0 with tag LSB=1 (s=0 epoch).
    hipMemsetAsync(ring, 0x01, (size_t)65536 * 4, stream);
    // scal + flags zero (contiguous)
    hipMemsetAsync(scal, 0, (8 + 1024) * sizeof(float), stream);

    embprep_kernel<<<2048, 256, 0, stream>>>(emb, embb, 30000 * 128);
    wprep_kernel<<<2048, 256, 0, stream>>>(w_ih_f, w_hh_f, w_ih_b, w_hh_b, wtile);
    lengths_kernel<<<Bsz, 256, 0, stream>>>(tag, lengths);

    void* kargs[] = {
        (void*)&bd, (void*)&embb, (void*)&wtile,
        (void*)&b_f, (void*)&b_b, (void*)&w_cls,
        (void*)&em_f, (void*)&em_b, (void*)&ring, (void*)&flags
    };
    hipLaunchCooperativeKernel((const void*)bilstm_persist,
                               dim3(256), dim3(256), kargs, 0, stream);

    golden_kernel<<<Bsz, 256, 0, stream>>>(tag, em_f, em_b, b_cls, trans, scal);
    crf_forward_kernel<<<Bsz, 64, 0, stream>>>(em_f, em_b, b_cls, trans, lengths, scal + 1);
    finalize_kernel<<<1, 1, 0, stream>>>(scal, out);
}

// Round 8
// 2413.147 us; speedup vs baseline: 1.2134x; 1.2134x over previous
//
#include <hip/hip_runtime.h>

#define Bsz 128
#define Lseq 512
#define Hdim 256
#define Tn 16
#define START_TAG 14
#define END_TAG 15

typedef float f32x4 __attribute__((ext_vector_type(4)));
typedef short s16x8 __attribute__((ext_vector_type(8)));

__device__ __forceinline__ unsigned int f2bf(float f) {
    unsigned int u = __builtin_bit_cast(unsigned int, f);
    u += 0x7fffu + ((u >> 16) & 1u);          // RNE
    return u >> 16;
}
__device__ __forceinline__ float bf2f(unsigned int bits16) {
    return __builtin_bit_cast(float, bits16 << 16);
}
__device__ __forceinline__ float sigmoidf_(float x) {
    return 1.0f / (1.0f + __expf(-x));
}

// emb fp32 [V*256] -> packed bf16 pairs [V*128]
__global__ void embprep_kernel(const float* __restrict__ emb,
                               unsigned int* __restrict__ embb, int n2) {
    int i = blockIdx.x * blockDim.x + threadIdx.x;
    int stride = gridDim.x * blockDim.x;
    for (; i < n2; i += stride)
        embb[i] = f2bf(emb[2 * i]) | (f2bf(emb[2 * i + 1]) << 16);
}

// wtile: per (dir, q, wv) slice of 4 col-tiles x 8 k-steps in MFMA B-frag order.
// wv<4: W_ih (pair p=wv), wv>=4: W_hh (pair p=wv-4).
// flat = ((((dir*4+q)*8+wv)*4+tt)*8+ks)*256 + lane*4 + j
// col(n,tt,p,q) = (n&3)*256 + q*64 + (p*4+tt)*4 + (n>>2); k = ks*32 + kq*8 + 2j
__global__ void wprep_kernel(const float* __restrict__ wih_f, const float* __restrict__ whh_f,
                             const float* __restrict__ wih_b, const float* __restrict__ whh_b,
                             unsigned int* __restrict__ wtile) {
    int flat = blockIdx.x * 256 + threadIdx.x;       // 0..524287
    int j    = flat & 3;
    int lane = (flat >> 2) & 63;
    int ks   = (flat >> 8) & 7;
    int tt   = (flat >> 11) & 3;
    int wv   = (flat >> 13) & 7;
    int q    = (flat >> 16) & 3;
    int dir  = flat >> 18;
    int p    = wv & 3;
    int n = lane & 15, kq = lane >> 4;
    int col = (n & 3) * 256 + q * 64 + (p * 4 + tt) * 4 + (n >> 2);
    int k0 = ks * 32 + kq * 8 + 2 * j;
    const float* w = (wv < 4) ? (dir ? wih_b : wih_f) : (dir ? whh_b : whh_f);
    float f0 = w[col * 256 + k0], f1 = w[col * 256 + k0 + 1];
    wtile[flat] = f2bf(f0) | (f2bf(f1) << 16);
}

// wclsb[dir][ks(8)][lane(64)][4]: B-frag of w_cls (col n = tag, k over dir's 256 h-dims)
__global__ void wclsprep_kernel(const float* __restrict__ w_cls,
                                unsigned int* __restrict__ wclsb) {
    int flat = blockIdx.x * 256 + threadIdx.x;       // 0..4095
    int j    = flat & 3;
    int lane = (flat >> 2) & 63;
    int ks   = (flat >> 8) & 7;
    int dir  = flat >> 11;
    int n = lane & 15, kq = lane >> 4;
    int k0 = ks * 32 + kq * 8 + 2 * j;
    float f0 = w_cls[n * 512 + dir * 256 + k0];
    float f1 = w_cls[n * 512 + dir * 256 + k0 + 1];
    wclsb[flat] = f2bf(f0) | (f2bf(f1) << 16);
}

__global__ void lengths_kernel(const int* __restrict__ tag, int* __restrict__ lengths) {
    int b = blockIdx.x;
    int tid = threadIdx.x;
    int cnt = 0;
    for (int l = tid; l < Lseq; l += blockDim.x)
        cnt += (tag[b * Lseq + l] != 0) ? 1 : 0;
    for (int off = 32; off > 0; off >>= 1) cnt += __shfl_down(cnt, off);
    __shared__ int red[4];
    if ((tid & 63) == 0) red[tid >> 6] = cnt;
    __syncthreads();
    if (tid == 0) lengths[b] = red[0] + red[1] + red[2] + red[3];
}

// Persistent BiLSTM: 64 WGs x 512 thr. WG = dir(2) x bg(8: 16 batches) x q(4: 64 units).
// Group = (dir,bg): 4 WGs share one 8KB/slot mailbox holding full h (tagged bf16).
// x-waves (wv<4): x-projection + bias for s+1 -> LDS (slack); wave p0 also does
// emission via MFMA. h-waves (wv>=4): critical path MFMA + cell + tagged store.
__global__ __launch_bounds__(512, 2) void bilstm_persist(
    const int* __restrict__ bd,
    const unsigned int* __restrict__ embb,     // [V][128]
    const unsigned int* __restrict__ wtile,
    const unsigned int* __restrict__ wclsb,
    const float* __restrict__ b_f, const float* __restrict__ b_b,
    float* __restrict__ em_f, float* __restrict__ em_b,
    unsigned int* __restrict__ mbox)           // [16 grp][2 slot][16 b][128 u]
{
    const int wg  = blockIdx.x;
    const int dir = wg >> 5;
    const int bg  = (wg >> 2) & 7;
    const int q   = wg & 3;
    const int tid = threadIdx.x;
    const int gb0 = bg * 16;

    __shared__ unsigned int h_lds[2][16 * 132];
    __shared__ f32x4 xp[2][16 * 64];           // [buf][tile T][lane]

    const int wv = tid >> 6;
    const int l  = tid & 63;
    const int n  = l & 15;
    const int kq = l >> 4;
    const bool is_h = (wv >= 4);
    const int p  = wv & 3;

    // ---- weights into VGPRs: 4 tiles x 8 k-steps x uint4 = 128 regs ----
    uint4 w_reg[4][8];
    {
        const unsigned int* wsrc =
            wtile + ((size_t)((dir * 4 + q) * 8 + wv)) * 8192 + l * 4;
        #pragma unroll
        for (int tt = 0; tt < 4; ++tt)
            #pragma unroll
            for (int ks = 0; ks < 8; ++ks)
                w_reg[tt][ks] = *(const uint4*)(wsrc + (tt * 8 + ks) * 256);
    }
    // bias per (lane, tile) col — used by x-waves' acc init
    float breg[4];
    {
        const float* bias = dir ? b_b : b_f;
        #pragma unroll
        for (int tt = 0; tt < 4; ++tt)
            breg[tt] = bias[(n & 3) * 256 + q * 64 + (p * 4 + tt) * 4 + (n >> 2)];
    }
    // emission B-frags (x-wave p0)
    uint4 wcls_reg[8];
    if (!is_h && p == 0) {
        const unsigned int* ws = wclsb + (size_t)dir * 2048 + l * 4;
        #pragma unroll
        for (int ks = 0; ks < 8; ++ks)
            wcls_reg[ks] = *(const uint4*)(ws + ks * 256);
    }

    float c_reg[4] = {0.f, 0.f, 0.f, 0.f};
    const int* bdr = bd + (size_t)(gb0 + n) * Lseq;
    unsigned int* mb = mbox + (size_t)(dir * 8 + bg) * 2 * 2048;
    float* emout = dir ? em_b : em_f;

    // poll identity: 512 threads cover 16 b x 32 uint4-chunks
    const int pb = tid >> 5, pc = tid & 31;

    // ---- prologue: x-waves fill xp[0] for t0 ----
    if (!is_h) {
        const int t0 = dir ? (Lseq - 1) : 0;
        int tok = bdr[t0];
        const unsigned int* xsrc = embb + (size_t)tok * 128 + kq * 4;
        f32x4 acc[4];
        #pragma unroll
        for (int tt = 0; tt < 4; ++tt) acc[tt] = {breg[tt], breg[tt], breg[tt], breg[tt]};
        #pragma unroll
        for (int ks = 0; ks < 8; ++ks) {
            s16x8 a = __builtin_bit_cast(s16x8, *(const uint4*)(xsrc + ks * 16));
            #pragma unroll
            for (int tt = 0; tt < 4; ++tt)
                acc[tt] = __builtin_amdgcn_mfma_f32_16x16x32_bf16(
                    a, __builtin_bit_cast(s16x8, w_reg[tt][ks]), acc[tt], 0, 0, 0);
        }
        #pragma unroll
        for (int tt = 0; tt < 4; ++tt) xp[0][(p * 4 + tt) * 64 + l] = acc[tt];
    }

    for (int s = 0; s < Lseq; ++s) {
        // ---- 1: poll own 4 data words (tag = epoch LSB), paced; stage to LDS ----
        {
            const unsigned int* src = mb + ((s + 1) & 1) * 2048 + pb * 128 + pc * 4;
            const unsigned int want = (((s + 3) >> 1) & 1) * 0x00010001u;
            unsigned int v0, v1, v2, v3;
            v0 = __hip_atomic_load(src + 0, __ATOMIC_RELAXED, __HIP_MEMORY_SCOPE_AGENT);
            v1 = __hip_atomic_load(src + 1, __ATOMIC_RELAXED, __HIP_MEMORY_SCOPE_AGENT);
            v2 = __hip_atomic_load(src + 2, __ATOMIC_RELAXED, __HIP_MEMORY_SCOPE_AGENT);
            v3 = __hip_atomic_load(src + 3, __ATOMIC_RELAXED, __HIP_MEMORY_SCOPE_AGENT);
            while (((v0 & 0x00010001u) != want) | ((v1 & 0x00010001u) != want) |
                   ((v2 & 0x00010001u) != want) | ((v3 & 0x00010001u) != want)) {
                __builtin_amdgcn_s_sleep(1);
                v0 = __hip_atomic_load(src + 0, __ATOMIC_RELAXED, __HIP_MEMORY_SCOPE_AGENT);
                v1 = __hip_atomic_load(src + 1, __ATOMIC_RELAXED, __HIP_MEMORY_SCOPE_AGENT);
                v2 = __hip_atomic_load(src + 2, __ATOMIC_RELAXED, __HIP_MEMORY_SCOPE_AGENT);
                v3 = __hip_atomic_load(src + 3, __ATOMIC_RELAXED, __HIP_MEMORY_SCOPE_AGENT);
            }
            *(uint4*)&h_lds[s & 1][pb * 132 + pc * 4] = make_uint4(v0, v1, v2, v3);
        }
        __syncthreads();

        if (is_h) {
            // ---- 2: critical path: xpart + 8x4 MFMAs + cell + tagged store ----
            f32x4 acc[4];
            #pragma unroll
            for (int tt = 0; tt < 4; ++tt) acc[tt] = xp[s & 1][(p * 4 + tt) * 64 + l];
            #pragma unroll
            for (int ks = 0; ks < 8; ++ks) {
                s16x8 a = *(const s16x8*)&h_lds[s & 1][n * 132 + ks * 16 + kq * 4];
                #pragma unroll
                for (int tt = 0; tt < 4; ++tt)
                    acc[tt] = __builtin_amdgcn_mfma_f32_16x16x32_bf16(
                        a, __builtin_bit_cast(s16x8, w_reg[tt][ks]), acc[tt], 0, 0, 0);
            }
            const unsigned int ep = (unsigned int)((s >> 1) & 1);
            const int base = l & ~3;
            const int rsel = n & 3;
            unsigned int* slot = mb + (s & 1) * 2048;
            #pragma unroll
            for (int tt = 0; tt < 4; ++tt) {
                float p0 = acc[tt][0], p1 = acc[tt][1], p2 = acc[tt][2], p3 = acc[tt][3];
                float a0, a1, a2, a3, gi, gf, gg, go;
                a0 = __shfl(p0, base);     a1 = __shfl(p1, base);
                a2 = __shfl(p2, base);     a3 = __shfl(p3, base);
                gi = (rsel == 0) ? a0 : (rsel == 1) ? a1 : (rsel == 2) ? a2 : a3;
                a0 = __shfl(p0, base + 1); a1 = __shfl(p1, base + 1);
                a2 = __shfl(p2, base + 1); a3 = __shfl(p3, base + 1);
                gf = (rsel == 0) ? a0 : (rsel == 1) ? a1 : (rsel == 2) ? a2 : a3;
                a0 = __shfl(p0, base + 2); a1 = __shfl(p1, base + 2);
                a2 = __shfl(p2, base + 2); a3 = __shfl(p3, base + 2);
                gg = (rsel == 0) ? a0 : (rsel == 1) ? a1 : (rsel == 2) ? a2 : a3;
                a0 = __shfl(p0, base + 3); a1 = __shfl(p1, base + 3);
                a2 = __shfl(p2, base + 3); a3 = __shfl(p3, base + 3);
                go = (rsel == 0) ? a0 : (rsel == 1) ? a1 : (rsel == 2) ? a2 : a3;
                float cn = sigmoidf_(gf) * c_reg[tt] + sigmoidf_(gi) * tanhf(gg);
                c_reg[tt] = cn;
                float hn = sigmoidf_(go) * tanhf(cn);
                unsigned int hb16 = (f2bf(hn) & 0xFFFEu) | ep;
                unsigned int partner = (unsigned int)__shfl((int)hb16, l + 4);
                if ((n & 4) == 0) {
                    int b = kq * 4 + rsel;
                    int uidx = q * 32 + p * 8 + tt * 2 + (n >> 3);
                    __hip_atomic_store(slot + b * 128 + uidx, hb16 | (partner << 16),
                                       __ATOMIC_RELAXED, __HIP_MEMORY_SCOPE_AGENT);
                }
            }
        } else {
            // ---- 3 (slack): x-projection + bias for s+1 ----
            if (s + 1 < Lseq) {
                const int tn = dir ? (Lseq - 2 - s) : (s + 1);
                int tok = bdr[tn];
                const unsigned int* xsrc = embb + (size_t)tok * 128 + kq * 4;
                f32x4 acc[4];
                #pragma unroll
                for (int tt = 0; tt < 4; ++tt)
                    acc[tt] = {breg[tt], breg[tt], breg[tt], breg[tt]};
                #pragma unroll
                for (int ks = 0; ks < 8; ++ks) {
                    s16x8 a = __builtin_bit_cast(s16x8, *(const uint4*)(xsrc + ks * 16));
                    #pragma unroll
                    for (int tt = 0; tt < 4; ++tt)
                        acc[tt] = __builtin_amdgcn_mfma_f32_16x16x32_bf16(
                            a, __builtin_bit_cast(s16x8, w_reg[tt][ks]), acc[tt], 0, 0, 0);
                }
                #pragma unroll
                for (int tt = 0; tt < 4; ++tt)
                    xp[(s + 1) & 1][(p * 4 + tt) * 64 + l] = acc[tt];
            }
            // ---- 4 (slack, wave p0): emission for t_prev via MFMA ----
            if (p == 0 && s > 0) {
                f32x4 eacc = {0.f, 0.f, 0.f, 0.f};
                #pragma unroll
                for (int ks = 0; ks < 8; ++ks) {
                    s16x8 a = *(const s16x8*)&h_lds[s & 1][n * 132 + ks * 16 + kq * 4];
                    eacc = __builtin_amdgcn_mfma_f32_16x16x32_bf16(
                        a, __builtin_bit_cast(s16x8, wcls_reg[ks]), eacc, 0, 0, 0);
                }
                int t_prev = dir ? (Lseq - s) : (s - 1);
                #pragma unroll
                for (int r = 0; r < 4; ++r)
                    emout[((size_t)(gb0 + kq * 4 + r) * Lseq + t_prev) * Tn + n] = eacc[r];
            }
        }
    }

    // ---- tail: stage h(L-1) and emit final timestep ----
    {
        const int s = Lseq;
        const unsigned int* src = mb + ((s + 1) & 1) * 2048 + pb * 128 + pc * 4;
        const unsigned int want = (((s + 3) >> 1) & 1) * 0x00010001u;
        unsigned int v0, v1, v2, v3;
        v0 = __hip_atomic_load(src + 0, __ATOMIC_RELAXED, __HIP_MEMORY_SCOPE_AGENT);
        v1 = __hip_atomic_load(src + 1, __ATOMIC_RELAXED, __HIP_MEMORY_SCOPE_AGENT);
        v2 = __hip_atomic_load(src + 2, __ATOMIC_RELAXED, __HIP_MEMORY_SCOPE_AGENT);
        v3 = __hip_atomic_load(src + 3, __ATOMIC_RELAXED, __HIP_MEMORY_SCOPE_AGENT);
        while (((v0 & 0x00010001u) != want) | ((v1 & 0x00010001u) != want) |
               ((v2 & 0x00010001u) != want) | ((v3 & 0x00010001u) != want)) {
            __builtin_amdgcn_s_sleep(1);
            v0 = __hip_atomic_load(src + 0, __ATOMIC_RELAXED, __HIP_MEMORY_SCOPE_AGENT);
            v1 = __hip_atomic_load(src + 1, __ATOMIC_RELAXED, __HIP_MEMORY_SCOPE_AGENT);
            v2 = __hip_atomic_load(src + 2, __ATOMIC_RELAXED, __HIP_MEMORY_SCOPE_AGENT);
            v3 = __hip_atomic_load(src + 3, __ATOMIC_RELAXED, __HIP_MEMORY_SCOPE_AGENT);
        }
        *(uint4*)&h_lds[0][pb * 132 + pc * 4] = make_uint4(v0, v1, v2, v3);
        __syncthreads();
        if (!is_h && p == 0) {
            f32x4 eacc = {0.f, 0.f, 0.f, 0.f};
            #pragma unroll
            for (int ks = 0; ks < 8; ++ks) {
                s16x8 a = *(const s16x8*)&h_lds[0][n * 132 + ks * 16 + kq * 4];
                eacc = __builtin_amdgcn_mfma_f32_16x16x32_bf16(
                    a, __builtin_bit_cast(s16x8, wcls_reg[ks]), eacc, 0, 0, 0);
            }
            int t_tail = dir ? 0 : (Lseq - 1);
            #pragma unroll
            for (int r = 0; r < 4; ++r)
                emout[((size_t)(gb0 + kq * 4 + r) * Lseq + t_tail) * Tn + n] = eacc[r];
        }
    }
}

__global__ void golden_kernel(const int* __restrict__ tag,
                              const float* __restrict__ em_f,
                              const float* __restrict__ em_b,
                              const float* __restrict__ b_cls,
                              const float* __restrict__ trans,
                              float* __restrict__ golden)
{
    int b = blockIdx.x;
    int tid = threadIdx.x;
    float s = 0.f;
    for (int l = tid; l < Lseq; l += blockDim.x) {
        int tg = tag[b * Lseq + l];
        if (tg != 0) {
            int prev = (l == 0) ? START_TAG : tag[b * Lseq + l - 1];
            size_t e = ((size_t)b * Lseq + l) * Tn + tg;
            s += em_f[e] + em_b[e] + b_cls[tg] + trans[prev * Tn + tg];
        }
    }
    for (int off = 32; off > 0; off >>= 1) s += __shfl_down(s, off);
    __shared__ float red[4];
    if ((tid & 63) == 0) red[tid >> 6] = s;
    __syncthreads();
    if (tid == 0) atomicAdd(golden, red[0] + red[1] + red[2] + red[3]);
}

__global__ void crf_forward_kernel(const float* __restrict__ em_f,
                                   const float* __restrict__ em_b,
                                   const float* __restrict__ b_cls,
                                   const float* __restrict__ trans,
                                   const int* __restrict__ lengths,
                                   float* __restrict__ allpath)
{
    int b = blockIdx.x;
    int lane = threadIdx.x;
    int j = lane & 15;
    float tcol[16];
    #pragma unroll
    for (int i = 0; i < 16; ++i) tcol[i] = trans[i * Tn + j];
    float bc = b_cls[j];
    size_t e0 = ((size_t)b * Lseq) * Tn + j;
    float alpha = em_f[e0] + em_b[e0] + bc + tcol[START_TAG];
    int len = lengths[b];
    for (int t = 1; t < Lseq; ++t) {
        float av[16];
        float m = -1e30f;
        #pragma unroll
        for (int i = 0; i < 16; ++i) {
            av[i] = __shfl(alpha, i) + tcol[i];
            m = fmaxf(m, av[i]);
        }
        float sum = 0.f;
        #pragma unroll
        for (int i = 0; i < 16; ++i) sum += __expf(av[i] - m);
        size_t e = ((size_t)b * Lseq + t) * Tn + j;
        float nv = em_f[e] + em_b[e] + bc + m + __logf(sum);
        alpha = (t < len) ? nv : alpha;
    }
    if (lane == END_TAG) atomicAdd(allpath, alpha);
}

__global__ void finalize_kernel(const float* __restrict__ scal, float* __restrict__ out) {
    out[0] = (scal[1] - scal[0]) / (float)Bsz;
}

extern "C" void kernel_launch(void* const* d_in, const int* in_sizes, int n_in,
                              void* d_out, int out_size, void* d_ws, size_t ws_size,
                              hipStream_t stream)
{
    (void)in_sizes; (void)n_in; (void)out_size; (void)ws_size;
    const int*   bd     = (const int*)d_in[0];
    const int*   tag    = (const int*)d_in[1];
    const float* emb    = (const float*)d_in[2];
    const float* w_ih_f = (const float*)d_in[3];
    const float* w_hh_f = (const float*)d_in[4];
    const float* b_f    = (const float*)d_in[5];
    const float* w_ih_b = (const float*)d_in[6];
    const float* w_hh_b = (const float*)d_in[7];
    const float* b_b    = (const float*)d_in[8];
    const float* w_cls  = (const float*)d_in[9];
    const float* b_cls  = (const float*)d_in[10];
    const float* trans  = (const float*)d_in[11];
    float* out = (float*)d_out;

    float* ws = (float*)d_ws;
    float* em_f = ws;                                         // 1048576 f
    float* em_b = em_f + (size_t)Bsz * Lseq * Tn;             // 1048576 f
    unsigned int* mbox = (unsigned int*)(em_b + (size_t)Bsz * Lseq * Tn);  // 16*2*2048
    float* scal = (float*)(mbox + 65536);                     // 8 f
    int* lengths = (int*)(scal + 8);                          // 128
    unsigned int* wtile = (unsigned int*)(lengths + 128);     // 524288
    unsigned int* wclsb = wtile + 524288;                     // 4096
    unsigned int* embb  = wclsb + 4096;                       // 30000*128

    // mailbox pre-fill: 0x01 bytes -> bf16 halves ~0 with tag LSB=1 (s=0 epoch)
    hipMemsetAsync(mbox, 0x01, (size_t)65536 * 4, stream);
    hipMemsetAsync(scal, 0, 8 * sizeof(float), stream);

    embprep_kernel<<<2048, 256, 0, stream>>>(emb, embb, 30000 * 128);
    wprep_kernel<<<2048, 256, 0, stream>>>(w_ih_f, w_hh_f, w_ih_b, w_hh_b, wtile);
    wclsprep_kernel<<<16, 256, 0, stream>>>(w_cls, wclsb);
    lengths_kernel<<<Bsz, 256, 0, stream>>>(tag, lengths);

    void* kargs[] = {
        (void*)&bd, (void*)&embb, (void*)&wtile, (void*)&wclsb,
        (void*)&b_f, (void*)&b_b,
        (void*)&em_f, (void*)&em_b, (void*)&mbox
    };
    hipLaunchCooperativeKernel((const void*)bilstm_persist,
                               dim3(64), dim3(512), kargs, 0, stream);

    golden_kernel<<<Bsz, 256, 0, stream>>>(tag, em_f, em_b, b_cls, trans, scal);
    crf_forward_kernel<<<Bsz, 64, 0, stream>>>(em_f, em_b, b_cls, trans, lengths, scal + 1);
    finalize_kernel<<<1, 1, 0, stream>>>(scal, out);
}